// Round 9
// baseline (3455.085 us; speedup 1.0000x reference)
//
#include <hip/hip_runtime.h>
#include <cstddef>
#include <cstdint>

// 2-layer LSTM decoder, B=2048, Z=64, H=256, D=8, T=250. fp32 in/out.
//
// R18 = R17 (2.76 ms, validated port-bound model: streamed weight bytes are
// the knob) with residency pushed to the LDS wall:
//  - h1f single-buffered (-8.25 KB): out-proj reads are strictly pre-B,
//    cell1 writes strictly post-B -> one barrier orders read vs overwrite.
//  - Wih0 x-tables packed bf16 (wxu, -16 KB): unpack = shift/mask per pair;
//    bf16 rel err (0.4%) == the i8-scale err already on the recurrent path.
//  - resident L0 tiles 0..11 (96 KB, was 8/64 KB); breg[8] -> breg[4]
//    (R10: depth-neutral; frees 16 VGPRs for unpack temps).
//  - slot math exact mod 4: L0 streams 12..31 (20), wraps to L1 0..3;
//    L1 streams 0..63 (64), wraps to next-step L0 12..15.
// Stream 704 -> 672 KB/step (-4.5%). LDS 160.1 KB of 163.8 (1 WG/CU).
// Go/no-go: VGPR<=128, FETCH ~14 MB, WRITE ~16 MB (explosion = spill).

#define BSZ    2048
#define ZDIM   64
#define HDIM   256
#define DDIM   8
#define TSTEPS 250
#define ROWS   16
#define NWG    (BSZ / ROWS)   // 128
#define NTH    512            // 8 waves
#define G4     1024
#define WSTR   264            // h1f/woutT row stride (shorts)

typedef __attribute__((ext_vector_type(4))) int v4i;

__device__ __forceinline__ unsigned short f2bf(float x) {   // RNE f32->bf16
  union { float f; unsigned u; } v; v.f = x;
  unsigned r = v.u + 0x7fff + ((v.u >> 16) & 1);
  return (unsigned short)(r >> 16);
}
__device__ __forceinline__ float bf2f(unsigned short b) {
  union { unsigned u; float f; } v; v.u = (unsigned)b << 16; return v.f;
}
__device__ __forceinline__ float bfl(unsigned u) {          // low bf16 of u32
  union { unsigned u; float f; } v; v.u = u << 16; return v.f;
}
__device__ __forceinline__ float bfh_(unsigned u) {         // high bf16 of u32
  union { unsigned u; float f; } v; v.u = u & 0xffff0000u; return v.f;
}
__device__ __forceinline__ float fexp2(float x) { return __builtin_amdgcn_exp2f(x); }
__device__ __forceinline__ float frcp(float x)  { return __builtin_amdgcn_rcpf(x); }
__device__ __forceinline__ float sigm(float x)  { return frcp(1.f + fexp2(-1.44269504f * x)); }
__device__ __forceinline__ float tanh_(float x) { return 2.f * frcp(1.f + fexp2(-2.88539008f * x)) - 1.f; }
__device__ __forceinline__ char q8(float x, float s) {
  float v = fminf(fmaxf(x * s, -127.f), 127.f);
  return (char)(int)__builtin_rintf(v);
}
// h*s split into hi + lo/254 (lo in [-127,127] exactly since 0.5*254=127)
__device__ __forceinline__ void q8pair(float h, float s, char* hi, char* lo) {
  float hs = fminf(fmaxf(h * s, -127.f), 127.f);
  float hq = __builtin_rintf(hs);
  *hi = (char)(int)hq;
  *lo = (char)(int)__builtin_rintf((hs - hq) * 254.f);
}

// ---------------- initial state (mapping verified R1-R8) ----------------
__global__ void init_state(const float* __restrict__ z,
                           const float* __restrict__ Wfh, const float* __restrict__ bfh,
                           const float* __restrict__ Wfc, const float* __restrict__ bfc,
                           char* __restrict__ h0h, char* __restrict__ h0l,
                           char* __restrict__ h1h, char* __restrict__ h1l,
                           float* __restrict__ c0s, float* __restrict__ c1s)
{
  int idx = blockIdx.x * 256 + threadIdx.x;
  int b = idx >> 8;
  int j = idx & 255;
  int col = ((b & 1) << 8) | j;
  const float* z0 = z + (size_t)(b >> 1) * ZDIM;
  const float* z1 = z + (size_t)(1024 + (b >> 1)) * ZDIM;
  float h0 = bfh[col], c0v = bfc[col], h1 = bfh[col], c1v = bfc[col];
  for (int k = 0; k < ZDIM; ++k) {
    float wh = Wfh[k * 512 + col];
    float wc = Wfc[k * 512 + col];
    float a = z0[k], bb = z1[k];
    h0  += a * wh;  c0v += a * wc;
    h1  += bb * wh; c1v += bb * wc;
  }
  char hi, lo;
  q8pair(h0, 31.75f, &hi, &lo); h0h[idx] = hi; h0l[idx] = lo;
  q8pair(h1, 31.75f, &hi, &lo); h1h[idx] = hi; h1l[idx] = lo;
  c0s[idx] = c0v; c1s[idx] = c1v;
}

// ---------------- per-output-column scales (unchanged) ----------------
__global__ void col_scales(const float* __restrict__ Whh0,
                           const float* __restrict__ Wih1, const float* __restrict__ Whh1,
                           float* __restrict__ cs0, float* __restrict__ qs0,
                           float* __restrict__ cs1, float* __restrict__ qs1)
{
  int c = blockIdx.x * 256 + threadIdx.x;   // 0..2047
  if (c < 1024) {
    float m = 0.f;
    for (int k = 0; k < 256; ++k) m = fmaxf(m, fabsf(Whh0[(size_t)k * G4 + c]));
    cs0[c] = m * (1.f / 16129.f);
    qs0[c] = 127.f / m;
  } else {
    c -= 1024;
    float m = 0.f;
    for (int k = 0; k < 256; ++k) m = fmaxf(m, fabsf(Whh1[(size_t)k * G4 + c]));
    for (int k = 0; k < 256; ++k) m = fmaxf(m, fabsf(Wih1[(size_t)k * G4 + c]));
    cs1[c] = m * (1.f / 16129.f);
    qs1[c] = 127.f / m;
  }
}

// ---- i8 weight pack: per-wave-contiguous linear stream (verified R8) ----
__global__ void pack_i8(const float* __restrict__ Whh0,
                        const float* __restrict__ Wih1, const float* __restrict__ Whh1,
                        const float* __restrict__ qs0, const float* __restrict__ qs1,
                        char* __restrict__ p0, char* __restrict__ p1)
{
  int tt   = blockIdx.x * 4 + (threadIdx.x >> 6);   // 0..767
  int lane = threadIdx.x & 63;
  int l15 = lane & 15, lq = lane >> 4;
  union { char c[16]; uint4 u; } v;
  if (tt < 256) {                                   // layer0: w*4+kc, i
    int w = tt >> 5, kc = (tt >> 3) & 3, i = tt & 7;
    int nt = (i >> 1) * 16 + 2 * w + (i & 1);
    int col = nt * 16 + l15;
    float q = qs0[col];
    for (int j = 0; j < 16; ++j) {
      int k = kc * 64 + lq * 16 + j;
      v.c[j] = q8(Whh0[(size_t)k * G4 + col], q);
    }
    *(uint4*)(p0 + (size_t)tt * 1024 + lane * 16) = v.u;
  } else {                                          // layer1: w*8+kc, i
    int t1 = tt - 256;
    int w = t1 >> 6, kc = (t1 >> 3) & 7, i = t1 & 7;
    int nt = (i >> 1) * 16 + 2 * w + (i & 1);
    int col = nt * 16 + l15;
    float q = qs1[col];
    for (int j = 0; j < 16; ++j) {
      int k = kc * 64 + lq * 16 + j;
      float wv = (k < 256) ? Whh1[(size_t)k * G4 + col]
                           : Wih1[(size_t)(k - 256) * G4 + col];
      v.c[j] = q8(wv, q);
    }
    *(uint4*)(p1 + (size_t)t1 * 1024 + lane * 16) = v.u;
  }
}

// ---------------- persistent LSTM kernel ----------------
__global__ __launch_bounds__(NTH, 1) void lstm_run(
    const float* __restrict__ target,
    const char* __restrict__ p0, const char* __restrict__ p1,
    const float* __restrict__ bih0, const float* __restrict__ bhh0,
    const float* __restrict__ bih1, const float* __restrict__ bhh1,
    const float* __restrict__ Wih0,            // [8,1024] fp32 -> bf16 LDS table
    const float* __restrict__ Wout, const float* __restrict__ bout,
    const char* __restrict__ h0h, const char* __restrict__ h0l,
    const char* __restrict__ h1h, const char* __restrict__ h1l,
    const float* __restrict__ c0s, const float* __restrict__ c1s,
    const float* __restrict__ cs0, const float* __restrict__ cs1,
    float* __restrict__ out)
{
  // double-buffered activation planes: [buf][32 blk-rows * 16], buf = 512 uint4
  __shared__ uint4 X4h[1024];                      // 16 KB
  __shared__ uint4 X4l[1024];                      // 16 KB
  __shared__ unsigned short h1f[16 * WSTR];        // 8.25 KB bf16 h1 (single buf)
  __shared__ unsigned short woutT[8 * WSTR];       // 4.1 KB bf16
  __shared__ uint4 wxu[1024];                      // 16 KB Wih0 bf16x8 per col
  __shared__ uint4 wres[8 * 12 * 64];              // 96 KB resident L0 tiles 0..11
                                                   // total ~156.4 KB
  const int tid  = threadIdx.x;
  const int w    = tid >> 6;
  const int lane = tid & 63;
  const int l15  = lane & 15;
  const int lq   = lane >> 4;
  const int b0   = blockIdx.x * ROWS;
  char* Xch = (char*)X4h;
  char* Xcl = (char*)X4l;

  // ---- one-time staging into buffer 0 ----
  {
    int m = tid & 15, blk = tid >> 4;              // 32 blks x 16 m
    const char* sh = (blk < 16) ? h1h : h0h;
    const char* sl = (blk < 16) ? h1l : h0l;
    int jblk = blk & 15;
    X4h[blk * 16 + m] = *(const uint4*)(sh + (size_t)(b0 + m) * HDIM + jblk * 16);
    X4l[blk * 16 + m] = *(const uint4*)(sl + (size_t)(b0 + m) * HDIM + jblk * 16);
  }
  for (int i = tid; i < HDIM * DDIM; i += NTH) {
    int k = i >> 3, d = i & 7;
    woutT[d * WSTR + k] = f2bf(Wout[i]);
  }
  for (int i = tid; i < G4; i += NTH) {            // packed bf16 pairs d={0..7}
    uint4 u;
    u.x = ((unsigned)f2bf(Wih0[1 * G4 + i]) << 16) | f2bf(Wih0[0 * G4 + i]);
    u.y = ((unsigned)f2bf(Wih0[3 * G4 + i]) << 16) | f2bf(Wih0[2 * G4 + i]);
    u.z = ((unsigned)f2bf(Wih0[5 * G4 + i]) << 16) | f2bf(Wih0[4 * G4 + i]);
    u.w = ((unsigned)f2bf(Wih0[7 * G4 + i]) << 16) | f2bf(Wih0[6 * G4 + i]);
    wxu[i] = u;
  }

  const int myrow = lq * 4;
  const int jc0   = 32 * w + l15;
  float c0r[2][4], c1r[2][4];
  float bA0[8], bA1[8], csA0[8], csA1[8];          // flat [g*2+cc]
#pragma unroll
  for (int i = 0; i < 8; ++i) {
    int col = (i >> 1) * 256 + jc0 + 16 * (i & 1);
    bA0[i]  = bih0[col] + bhh0[col];
    bA1[i]  = bih1[col] + bhh1[col];
    csA0[i] = cs0[col];
    csA1[i] = cs1[col];
  }
#pragma unroll
  for (int cc = 0; cc < 2; ++cc) {
    int j = jc0 + cc * 16;
#pragma unroll
    for (int r = 0; r < 4; ++r) {
      c0r[cc][r] = c0s[(size_t)(b0 + myrow + r) * HDIM + j];
      c1r[cc][r] = c1s[(size_t)(b0 + myrow + r) * HDIM + j];
    }
  }
  const int opr = tid >> 5, opd = (tid >> 2) & 7, opq = tid & 3;
  const float bo_out = bout[opd];

  // per-lane weight stream bases; tile j at base + j*1024 (linear)
  const char* gp0 = p0 + (size_t)w * 32768 + lane * 16;
  const char* gp1 = p1 + (size_t)w * 65536 + lane * 16;

  // ---- resident L0 tiles 0..11 (per wave), loaded once ----
#pragma unroll
  for (int j = 0; j < 12; ++j)
    wres[w * 768 + j * 64 + lane] = *(const uint4*)(gp0 + (size_t)j * 1024);

  // 4-deep direct global->VGPR stream for the non-resident tiles.
  // prologue: L0 streamed tiles 12..15 -> breg[0..3]  (slot = j&3, 12%4==0)
  v4i breg[4];
#pragma unroll
  for (int s = 0; s < 4; ++s)
    breg[s] = *(const v4i*)(gp0 + (size_t)(12 + s) * 1024);

  __syncthreads();

#pragma unroll 1
  for (int t = 0; t < TSTEPS; ++t) {
    const int xc = (t & 1) << 9;                   // uint4-index base of X_cur
    const int xn = xc ^ 512;                       // X_next

    // ---- teacher-forced input: each thread loads its own 4 rows ----
    float4 xa[4], xb[4];
    if (t > 0) {
      const float* xp = target + (size_t)(b0 + myrow) * (TSTEPS * DDIM)
                               + (size_t)(t - 1) * DDIM;
#pragma unroll
      for (int r = 0; r < 4; ++r) {
        xa[r] = *(const float4*)(xp + (size_t)r * (TSTEPS * DDIM));
        xb[r] = *(const float4*)(xp + (size_t)r * (TSTEPS * DDIM) + 4);
      }
    } else {
#pragma unroll
      for (int r = 0; r < 4; ++r) {
        xa[r] = make_float4(0.f, 0.f, 0.f, 0.f);
        xb[r] = make_float4(0.f, 0.f, 0.f, 0.f);
      }
    }

    const float sc0 = (t <= 1) ? 4.f : 1.f;
    const float sc1 = (t == 0) ? 4.f : 1.f;
    const float wq0 = (t == 0) ? 31.75f : 127.f;

    v4i acch[8], accl[8];
    const v4i zi = {0, 0, 0, 0};

    // ============ layer 0: h0 @ Whh0 ============
#pragma unroll
    for (int i = 0; i < 8; ++i) { acch[i] = zi; accl[i] = zi; }
    {
      v4i ah, al;
      {                                            // kc=0 A-fragment
        int aidx = xc + (16 + lq) * 16 + l15;
        ah = __builtin_bit_cast(v4i, X4h[aidx]);
        al = __builtin_bit_cast(v4i, X4l[aidx]);
      }
      // resident tiles 0..11 from LDS: 2-slot rotation (static idx, R17-proven)
      {
        v4i rb[2];
        rb[0] = __builtin_bit_cast(v4i, wres[w * 768 + lane]);
#pragma unroll
        for (int j = 0; j < 12; ++j) {
          if (j == 8) {                            // kc=1 A-fragment
            int aidx = xc + (16 + 4 + lq) * 16 + l15;
            ah = __builtin_bit_cast(v4i, X4h[aidx]);
            al = __builtin_bit_cast(v4i, X4l[aidx]);
          }
          if (j < 11)
            rb[(j + 1) & 1] = __builtin_bit_cast(v4i, wres[w * 768 + (j + 1) * 64 + lane]);
          v4i bb = rb[j & 1];
          const int i = j & 7;
          acch[i] = __builtin_amdgcn_mfma_i32_16x16x64_i8(ah, bb, acch[i], 0, 0, 0);
          accl[i] = __builtin_amdgcn_mfma_i32_16x16x64_i8(al, bb, accl[i], 0, 0, 0);
        }
      }
      // streamed tiles 12..31 (slot = j&3); kc=1 frag still current at j=12
#pragma unroll 4
      for (int j = 12; j < 32; ++j) {
        const int i = j & 7, s = j & 3;
        if (i == 0) {                              // j=16,24: kc=2,3
          int kc = j >> 3;
          int aidx = xc + (16 + kc * 4 + lq) * 16 + l15;
          ah = __builtin_bit_cast(v4i, X4h[aidx]);
          al = __builtin_bit_cast(v4i, X4l[aidx]);
        }
        v4i bb = breg[s];
        acch[i] = __builtin_amdgcn_mfma_i32_16x16x64_i8(ah, bb, acch[i], 0, 0, 0);
        accl[i] = __builtin_amdgcn_mfma_i32_16x16x64_i8(al, bb, accl[i], 0, 0, 0);
        const int jn = j + 4;
        breg[s] = (jn < 32) ? *(const v4i*)(gp0 + (size_t)jn * 1024)
                            : *(const v4i*)(gp1 + (size_t)(jn - 32) * 1024);
      }
    }

    // ---- deferred out-projection for step t-1 (pre-B reads, post-B writes) ----
    if (t > 0) {
      float s_ = 0.f;
#pragma unroll
      for (int i = 0; i < 16; ++i) {
        ushort4 hx = *(const ushort4*)&h1f[opr * WSTR + i * 16 + opq * 4];
        ushort4 wv = *(const ushort4*)&woutT[opd * WSTR + i * 16 + opq * 4];
        s_ += bf2f(hx.x) * bf2f(wv.x) + bf2f(hx.y) * bf2f(wv.y)
            + bf2f(hx.z) * bf2f(wv.z) + bf2f(hx.w) * bf2f(wv.w);
      }
      s_ += __shfl_xor(s_, 1);
      s_ += __shfl_xor(s_, 2);
      if (opq == 0)
        out[(size_t)(b0 + opr) * (TSTEPS * DDIM) + (size_t)(t - 1) * DDIM + opd] =
            s_ + bo_out;
    }

    // ---- cell 0: dequant + bf16 x-path (wxu unpack); h0(t) -> X_next ----
    {
#pragma unroll
      for (int cc = 0; cc < 2; ++cc) {
        float gf4[4][4];
#pragma unroll
        for (int g = 0; g < 4; ++g) {
          int i = g * 2 + cc;
          int col = g * 256 + jc0 + cc * 16;
          uint4 u = wxu[col];
          float w0 = bfl(u.x), w1 = bfh_(u.x);
          float w2 = bfl(u.y), w3 = bfh_(u.y);
          float w4 = bfl(u.z), w5 = bfh_(u.z);
          float w6 = bfl(u.w), w7 = bfh_(u.w);
          float cs = csA0[i] * sc0;
#pragma unroll
          for (int r = 0; r < 4; ++r)
            gf4[g][r] = ((float)acch[i][r] + (float)accl[i][r] * (1.f / 254.f)) * cs + bA0[i]
                + xa[r].x * w0 + xa[r].y * w1 + xa[r].z * w2 + xa[r].w * w3
                + xb[r].x * w4 + xb[r].y * w5 + xb[r].z * w6 + xb[r].w * w7;
        }
#pragma unroll
        for (int r = 0; r < 4; ++r) {
          float iv = sigm(gf4[0][r]);
          float fv = sigm(gf4[1][r]);
          float gv = tanh_(gf4[2][r]);
          float ov = sigm(gf4[3][r]);
          c0r[cc][r] = fv * c0r[cc][r] + iv * gv;
          char hi, lo;
          q8pair(ov * tanh_(c0r[cc][r]), wq0, &hi, &lo);
          int off = (xn + (16 + 2 * w + cc) * 16 + myrow + r) * 16 + l15;
          Xch[off] = hi; Xcl[off] = lo;
        }
      }
    }
    __syncthreads();   // (B) h0(t) visible; L1 prologue tiles 0..3 landed

    // ====== layer 1: [h1(t-1) | h0(t)] @ W1 (64 tiles, slot = j&3) ======
#pragma unroll
    for (int i = 0; i < 8; ++i) { acch[i] = zi; accl[i] = zi; }
    {
      v4i ah, al;
#pragma unroll 8
      for (int j = 0; j < 64; ++j) {
        const int i = j & 7, s = j & 3;
        if (i == 0) {
          int kc = j >> 3;                         // 0..3 h1 (cur), 4..7 h0' (next)
          int aidx = (kc < 4) ? (xc + (kc * 4 + lq) * 16 + l15)
                              : (xn + (16 + (kc - 4) * 4 + lq) * 16 + l15);
          ah = __builtin_bit_cast(v4i, X4h[aidx]);
          al = __builtin_bit_cast(v4i, X4l[aidx]);
        }
        acch[i] = __builtin_amdgcn_mfma_i32_16x16x64_i8(ah, breg[s], acch[i], 0, 0, 0);
        accl[i] = __builtin_amdgcn_mfma_i32_16x16x64_i8(al, breg[s], accl[i], 0, 0, 0);
        const int jn = j + 4;
        // wrap: next-step L0 streamed tiles start at 12 (0..11 are resident)
        breg[s] = (jn < 64) ? *(const v4i*)(gp1 + (size_t)jn * 1024)
                            : *(const v4i*)(gp0 + (size_t)(jn - 64 + 12) * 1024);
      }
    }

    // ---- cell 1: writes h1(t) into X_next + bf16 h1f ----
#pragma unroll
    for (int cc = 0; cc < 2; ++cc)
#pragma unroll
      for (int r = 0; r < 4; ++r) {
        float di = ((float)acch[0 + cc][r] + (float)accl[0 + cc][r] * (1.f / 254.f));
        float df = ((float)acch[2 + cc][r] + (float)accl[2 + cc][r] * (1.f / 254.f));
        float dg = ((float)acch[4 + cc][r] + (float)accl[4 + cc][r] * (1.f / 254.f));
        float dv = ((float)acch[6 + cc][r] + (float)accl[6 + cc][r] * (1.f / 254.f));
        float iv = sigm(di * csA1[0 + cc] * sc1 + bA1[0 + cc]);
        float fv = sigm(df * csA1[2 + cc] * sc1 + bA1[2 + cc]);
        float gv = tanh_(dg * csA1[4 + cc] * sc1 + bA1[4 + cc]);
        float ov = sigm(dv * csA1[6 + cc] * sc1 + bA1[6 + cc]);
        c1r[cc][r] = fv * c1r[cc][r] + iv * gv;
        float h = ov * tanh_(c1r[cc][r]);
        char hi, lo;
        q8pair(h, 127.f, &hi, &lo);
        int off = (xn + (2 * w + cc) * 16 + myrow + r) * 16 + l15;
        Xch[off] = hi; Xcl[off] = lo;
        h1f[(myrow + r) * WSTR + jc0 + cc * 16] = f2bf(h);
      }
    __syncthreads();   // (F) h1(t)/h1f visible; next-step L0 tiles 12..15 landed
  }

  // ---- epilogue: out-projection for the final step ----
  {
    float s_ = 0.f;
#pragma unroll
    for (int i = 0; i < 16; ++i) {
      ushort4 hx = *(const ushort4*)&h1f[opr * WSTR + i * 16 + opq * 4];
      ushort4 wv = *(const ushort4*)&woutT[opd * WSTR + i * 16 + opq * 4];
      s_ += bf2f(hx.x) * bf2f(wv.x) + bf2f(hx.y) * bf2f(wv.y)
          + bf2f(hx.z) * bf2f(wv.z) + bf2f(hx.w) * bf2f(wv.w);
    }
    s_ += __shfl_xor(s_, 1);
    s_ += __shfl_xor(s_, 2);
    if (opq == 0)
      out[(size_t)(b0 + opr) * (TSTEPS * DDIM) + (size_t)(TSTEPS - 1) * DDIM + opd] =
          s_ + bo_out;
  }
}

extern "C" void kernel_launch(void* const* d_in, const int* in_sizes, int n_in,
                              void* d_out, int out_size, void* d_ws, size_t ws_size,
                              hipStream_t stream) {
  const float* z    = (const float*)d_in[0];
  const float* tgt  = (const float*)d_in[1];
  const float* Wfh  = (const float*)d_in[2];
  const float* bfh  = (const float*)d_in[3];
  const float* Wfc  = (const float*)d_in[4];
  const float* bfc  = (const float*)d_in[5];
  const float* Wih0 = (const float*)d_in[6];
  const float* Whh0 = (const float*)d_in[7];
  const float* bih0 = (const float*)d_in[8];
  const float* bhh0 = (const float*)d_in[9];
  const float* Wih1 = (const float*)d_in[10];
  const float* Whh1 = (const float*)d_in[11];
  const float* bih1 = (const float*)d_in[12];
  const float* bhh1 = (const float*)d_in[13];
  const float* Wout = (const float*)d_in[14];
  const float* bout = (const float*)d_in[15];

  // ws layout (bytes), total ~7.09 MB
  char* ws = (char*)d_ws;
  char*  p0   = ws;                                  // 262,144
  char*  p1   = ws + 262144;                         // 524,288
  char*  h0h  = ws + 786432;                         // 524,288
  char*  h0l  = ws + 1310720;                        // 524,288
  char*  h1h  = ws + 1835008;                        // 524,288
  char*  h1l  = ws + 2359296;                        // 524,288
  float* c0s  = (float*)(ws + 2883584);              // 2,097,152
  float* c1s  = (float*)(ws + 4980736);              // 2,097,152
  float* cs0  = (float*)(ws + 7077888);              // 4,096
  float* qs0  = (float*)(ws + 7081984);              // 4,096
  float* cs1  = (float*)(ws + 7086080);              // 4,096
  float* qs1  = (float*)(ws + 7090176);              // 4,096

  hipLaunchKernelGGL(init_state, dim3(BSZ * HDIM / 256), dim3(256), 0, stream,
                     z, Wfh, bfh, Wfc, bfc, h0h, h0l, h1h, h1l, c0s, c1s);
  hipLaunchKernelGGL(col_scales, dim3(8), dim3(256), 0, stream,
                     Whh0, Wih1, Whh1, cs0, qs0, cs1, qs1);
  hipLaunchKernelGGL(pack_i8, dim3(192), dim3(256), 0, stream,
                     Whh0, Wih1, Whh1, qs0, qs1, p0, p1);
  hipLaunchKernelGGL(lstm_run, dim3(NWG), dim3(NTH), 0, stream,
                     tgt, p0, p1, bih0, bhh0, bih1, bhh1, Wih0, Wout, bout,
                     h0h, h0l, h1h, h1l, c0s, c1s, cs0, cs1, (float*)d_out);
}

// Round 10
// 2998.128 us; speedup vs baseline: 1.1524x; 1.1524x over previous
//
#include <hip/hip_runtime.h>
#include <cstddef>
#include <cstdint>

// 2-layer LSTM decoder, B=2048, Z=64, H=256, D=8, T=250. fp32 in/out.
//
// R19 = R18 (12 resident L0 tiles, wxu bf16 x-tables, single h1f) with the
// ring depth restored to 8. R18's +25% regression (no spill, clean counters)
// is attributed to breg[4]: per-wave latency coverage halved on the 84-tile
// stream. The mod-8 constraint (84 % 8 == 4) is solved by a period-2 slot
// offset: slot(j) = (j+4+O)&7 for BOTH phases (L0 j=12..31, L1 j=0..63;
// -12 == +20 == +4 mod 8), O alternating 0/4 per step. Step body is a
// generic lambda instantiated at O=0 and O=4 (constexpr -> all breg indices
// static). x-loads moved after the L0 stream (R13 placement) to pay the
// +16 VGPR for breg[8]. Continuity verified at all seams:
//   L0 j=24..31 prefetch L1 0..7 -> slot (4+O)&7 = L1 consume slot ✓
//   L1 j=56..63 prefetch next L0 12..19 -> consume at O'=O+4 ✓
//   prologue (O=0): tile 12+s -> slot s ✓
// Stream 672 KB/step (-4.5% vs R17). LDS ~160.1 KB.
// Go/no-go: VGPR<=128, FETCH ~14.5 MB, WRITE ~16 MB (explosion = spill).

#define BSZ    2048
#define ZDIM   64
#define HDIM   256
#define DDIM   8
#define TSTEPS 250
#define ROWS   16
#define NWG    (BSZ / ROWS)   // 128
#define NTH    512            // 8 waves
#define G4     1024
#define WSTR   264            // h1f/woutT row stride (shorts)

typedef __attribute__((ext_vector_type(4))) int v4i;

struct IcO0 { static constexpr int v = 0; };
struct IcO4 { static constexpr int v = 4; };

__device__ __forceinline__ unsigned short f2bf(float x) {   // RNE f32->bf16
  union { float f; unsigned u; } v; v.f = x;
  unsigned r = v.u + 0x7fff + ((v.u >> 16) & 1);
  return (unsigned short)(r >> 16);
}
__device__ __forceinline__ float bf2f(unsigned short b) {
  union { unsigned u; float f; } v; v.u = (unsigned)b << 16; return v.f;
}
__device__ __forceinline__ float bfl(unsigned u) {          // low bf16 of u32
  union { unsigned u; float f; } v; v.u = u << 16; return v.f;
}
__device__ __forceinline__ float bfh_(unsigned u) {         // high bf16 of u32
  union { unsigned u; float f; } v; v.u = u & 0xffff0000u; return v.f;
}
__device__ __forceinline__ float fexp2(float x) { return __builtin_amdgcn_exp2f(x); }
__device__ __forceinline__ float frcp(float x)  { return __builtin_amdgcn_rcpf(x); }
__device__ __forceinline__ float sigm(float x)  { return frcp(1.f + fexp2(-1.44269504f * x)); }
__device__ __forceinline__ float tanh_(float x) { return 2.f * frcp(1.f + fexp2(-2.88539008f * x)) - 1.f; }
__device__ __forceinline__ char q8(float x, float s) {
  float v = fminf(fmaxf(x * s, -127.f), 127.f);
  return (char)(int)__builtin_rintf(v);
}
// h*s split into hi + lo/254 (lo in [-127,127] exactly since 0.5*254=127)
__device__ __forceinline__ void q8pair(float h, float s, char* hi, char* lo) {
  float hs = fminf(fmaxf(h * s, -127.f), 127.f);
  float hq = __builtin_rintf(hs);
  *hi = (char)(int)hq;
  *lo = (char)(int)__builtin_rintf((hs - hq) * 254.f);
}

// ---------------- initial state (mapping verified R1-R8) ----------------
__global__ void init_state(const float* __restrict__ z,
                           const float* __restrict__ Wfh, const float* __restrict__ bfh,
                           const float* __restrict__ Wfc, const float* __restrict__ bfc,
                           char* __restrict__ h0h, char* __restrict__ h0l,
                           char* __restrict__ h1h, char* __restrict__ h1l,
                           float* __restrict__ c0s, float* __restrict__ c1s)
{
  int idx = blockIdx.x * 256 + threadIdx.x;
  int b = idx >> 8;
  int j = idx & 255;
  int col = ((b & 1) << 8) | j;
  const float* z0 = z + (size_t)(b >> 1) * ZDIM;
  const float* z1 = z + (size_t)(1024 + (b >> 1)) * ZDIM;
  float h0 = bfh[col], c0v = bfc[col], h1 = bfh[col], c1v = bfc[col];
  for (int k = 0; k < ZDIM; ++k) {
    float wh = Wfh[k * 512 + col];
    float wc = Wfc[k * 512 + col];
    float a = z0[k], bb = z1[k];
    h0  += a * wh;  c0v += a * wc;
    h1  += bb * wh; c1v += bb * wc;
  }
  char hi, lo;
  q8pair(h0, 31.75f, &hi, &lo); h0h[idx] = hi; h0l[idx] = lo;
  q8pair(h1, 31.75f, &hi, &lo); h1h[idx] = hi; h1l[idx] = lo;
  c0s[idx] = c0v; c1s[idx] = c1v;
}

// ---------------- per-output-column scales (unchanged) ----------------
__global__ void col_scales(const float* __restrict__ Whh0,
                           const float* __restrict__ Wih1, const float* __restrict__ Whh1,
                           float* __restrict__ cs0, float* __restrict__ qs0,
                           float* __restrict__ cs1, float* __restrict__ qs1)
{
  int c = blockIdx.x * 256 + threadIdx.x;   // 0..2047
  if (c < 1024) {
    float m = 0.f;
    for (int k = 0; k < 256; ++k) m = fmaxf(m, fabsf(Whh0[(size_t)k * G4 + c]));
    cs0[c] = m * (1.f / 16129.f);
    qs0[c] = 127.f / m;
  } else {
    c -= 1024;
    float m = 0.f;
    for (int k = 0; k < 256; ++k) m = fmaxf(m, fabsf(Whh1[(size_t)k * G4 + c]));
    for (int k = 0; k < 256; ++k) m = fmaxf(m, fabsf(Wih1[(size_t)k * G4 + c]));
    cs1[c] = m * (1.f / 16129.f);
    qs1[c] = 127.f / m;
  }
}

// ---- i8 weight pack: per-wave-contiguous linear stream (verified R8) ----
__global__ void pack_i8(const float* __restrict__ Whh0,
                        const float* __restrict__ Wih1, const float* __restrict__ Whh1,
                        const float* __restrict__ qs0, const float* __restrict__ qs1,
                        char* __restrict__ p0, char* __restrict__ p1)
{
  int tt   = blockIdx.x * 4 + (threadIdx.x >> 6);   // 0..767
  int lane = threadIdx.x & 63;
  int l15 = lane & 15, lq = lane >> 4;
  union { char c[16]; uint4 u; } v;
  if (tt < 256) {                                   // layer0: w*4+kc, i
    int w = tt >> 5, kc = (tt >> 3) & 3, i = tt & 7;
    int nt = (i >> 1) * 16 + 2 * w + (i & 1);
    int col = nt * 16 + l15;
    float q = qs0[col];
    for (int j = 0; j < 16; ++j) {
      int k = kc * 64 + lq * 16 + j;
      v.c[j] = q8(Whh0[(size_t)k * G4 + col], q);
    }
    *(uint4*)(p0 + (size_t)tt * 1024 + lane * 16) = v.u;
  } else {                                          // layer1: w*8+kc, i
    int t1 = tt - 256;
    int w = t1 >> 6, kc = (t1 >> 3) & 7, i = t1 & 7;
    int nt = (i >> 1) * 16 + 2 * w + (i & 1);
    int col = nt * 16 + l15;
    float q = qs1[col];
    for (int j = 0; j < 16; ++j) {
      int k = kc * 64 + lq * 16 + j;
      float wv = (k < 256) ? Whh1[(size_t)k * G4 + col]
                           : Wih1[(size_t)(k - 256) * G4 + col];
      v.c[j] = q8(wv, q);
    }
    *(uint4*)(p1 + (size_t)t1 * 1024 + lane * 16) = v.u;
  }
}

// ---------------- persistent LSTM kernel ----------------
__global__ __launch_bounds__(NTH, 1) void lstm_run(
    const float* __restrict__ target,
    const char* __restrict__ p0, const char* __restrict__ p1,
    const float* __restrict__ bih0, const float* __restrict__ bhh0,
    const float* __restrict__ bih1, const float* __restrict__ bhh1,
    const float* __restrict__ Wih0,            // [8,1024] fp32 -> bf16 LDS table
    const float* __restrict__ Wout, const float* __restrict__ bout,
    const char* __restrict__ h0h, const char* __restrict__ h0l,
    const char* __restrict__ h1h, const char* __restrict__ h1l,
    const float* __restrict__ c0s, const float* __restrict__ c1s,
    const float* __restrict__ cs0, const float* __restrict__ cs1,
    float* __restrict__ out)
{
  // double-buffered activation planes: [buf][32 blk-rows * 16], buf = 512 uint4
  __shared__ uint4 X4h[1024];                      // 16 KB
  __shared__ uint4 X4l[1024];                      // 16 KB
  __shared__ unsigned short h1f[16 * WSTR];        // 8.25 KB bf16 h1 (single buf)
  __shared__ unsigned short woutT[8 * WSTR];       // 4.1 KB bf16
  __shared__ uint4 wxu[1024];                      // 16 KB Wih0 bf16x8 per col
  __shared__ uint4 wres[8 * 12 * 64];              // 96 KB resident L0 tiles 0..11
                                                   // total ~160.1 KB
  const int tid  = threadIdx.x;
  const int w    = tid >> 6;
  const int lane = tid & 63;
  const int l15  = lane & 15;
  const int lq   = lane >> 4;
  const int b0   = blockIdx.x * ROWS;
  char* Xch = (char*)X4h;
  char* Xcl = (char*)X4l;

  // ---- one-time staging into buffer 0 ----
  {
    int m = tid & 15, blk = tid >> 4;              // 32 blks x 16 m
    const char* sh = (blk < 16) ? h1h : h0h;
    const char* sl = (blk < 16) ? h1l : h0l;
    int jblk = blk & 15;
    X4h[blk * 16 + m] = *(const uint4*)(sh + (size_t)(b0 + m) * HDIM + jblk * 16);
    X4l[blk * 16 + m] = *(const uint4*)(sl + (size_t)(b0 + m) * HDIM + jblk * 16);
  }
  for (int i = tid; i < HDIM * DDIM; i += NTH) {
    int k = i >> 3, d = i & 7;
    woutT[d * WSTR + k] = f2bf(Wout[i]);
  }
  for (int i = tid; i < G4; i += NTH) {            // packed bf16 pairs d={0..7}
    uint4 u;
    u.x = ((unsigned)f2bf(Wih0[1 * G4 + i]) << 16) | f2bf(Wih0[0 * G4 + i]);
    u.y = ((unsigned)f2bf(Wih0[3 * G4 + i]) << 16) | f2bf(Wih0[2 * G4 + i]);
    u.z = ((unsigned)f2bf(Wih0[5 * G4 + i]) << 16) | f2bf(Wih0[4 * G4 + i]);
    u.w = ((unsigned)f2bf(Wih0[7 * G4 + i]) << 16) | f2bf(Wih0[6 * G4 + i]);
    wxu[i] = u;
  }

  const int myrow = lq * 4;
  const int jc0   = 32 * w + l15;
  float c0r[2][4], c1r[2][4];
  float bA0[8], bA1[8], csA0[8], csA1[8];          // flat [g*2+cc]
#pragma unroll
  for (int i = 0; i < 8; ++i) {
    int col = (i >> 1) * 256 + jc0 + 16 * (i & 1);
    bA0[i]  = bih0[col] + bhh0[col];
    bA1[i]  = bih1[col] + bhh1[col];
    csA0[i] = cs0[col];
    csA1[i] = cs1[col];
  }
#pragma unroll
  for (int cc = 0; cc < 2; ++cc) {
    int j = jc0 + cc * 16;
#pragma unroll
    for (int r = 0; r < 4; ++r) {
      c0r[cc][r] = c0s[(size_t)(b0 + myrow + r) * HDIM + j];
      c1r[cc][r] = c1s[(size_t)(b0 + myrow + r) * HDIM + j];
    }
  }
  const int opr = tid >> 5, opd = (tid >> 2) & 7, opq = tid & 3;
  const float bo_out = bout[opd];

  // per-lane weight stream bases; tile j at base + j*1024 (linear)
  const char* gp0 = p0 + (size_t)w * 32768 + lane * 16;
  const char* gp1 = p1 + (size_t)w * 65536 + lane * 16;

  // ---- resident L0 tiles 0..11 (per wave), loaded once ----
#pragma unroll
  for (int j = 0; j < 12; ++j)
    wres[w * 768 + j * 64 + lane] = *(const uint4*)(gp0 + (size_t)j * 1024);

  // 8-deep stream; prologue (O=0): L0 tile 12+s -> slot (12+s+4)&7 = s
  v4i breg[8];
#pragma unroll
  for (int s = 0; s < 8; ++s)
    breg[s] = *(const v4i*)(gp0 + (size_t)(12 + s) * 1024);

  __syncthreads();

  // ---- one LSTM step; O = stream slot offset (0 or 4), compile-time ----
  auto step = [&](int t, auto tag) __attribute__((always_inline)) {
    constexpr int O = decltype(tag)::v;
    const int xc = (t & 1) << 9;                   // uint4-index base of X_cur
    const int xn = xc ^ 512;                       // X_next

    const float sc0 = (t <= 1) ? 4.f : 1.f;
    const float sc1 = (t == 0) ? 4.f : 1.f;
    const float wq0 = (t == 0) ? 31.75f : 127.f;

    v4i acch[8], accl[8];
    const v4i zi = {0, 0, 0, 0};

    // ============ layer 0: h0 @ Whh0 ============
#pragma unroll
    for (int i = 0; i < 8; ++i) { acch[i] = zi; accl[i] = zi; }
    {
      v4i ah, al;
      {                                            // kc=0 A-fragment
        int aidx = xc + (16 + lq) * 16 + l15;
        ah = __builtin_bit_cast(v4i, X4h[aidx]);
        al = __builtin_bit_cast(v4i, X4l[aidx]);
      }
      // resident tiles 0..11 from LDS: 2-slot rotation (static idx)
      {
        v4i rb[2];
        rb[0] = __builtin_bit_cast(v4i, wres[w * 768 + lane]);
#pragma unroll
        for (int j = 0; j < 12; ++j) {
          if (j == 8) {                            // kc=1 A-fragment
            int aidx = xc + (16 + 4 + lq) * 16 + l15;
            ah = __builtin_bit_cast(v4i, X4h[aidx]);
            al = __builtin_bit_cast(v4i, X4l[aidx]);
          }
          if (j < 11)
            rb[(j + 1) & 1] = __builtin_bit_cast(v4i, wres[w * 768 + (j + 1) * 64 + lane]);
          v4i bb = rb[j & 1];
          const int i = j & 7;
          acch[i] = __builtin_amdgcn_mfma_i32_16x16x64_i8(ah, bb, acch[i], 0, 0, 0);
          accl[i] = __builtin_amdgcn_mfma_i32_16x16x64_i8(al, bb, accl[i], 0, 0, 0);
        }
      }
      // streamed tiles 12..31 (slot = (j+4+O)&7); kc=1 frag current at j=12
#pragma unroll
      for (int j = 12; j < 32; ++j) {
        const int i = j & 7, s = (j + 4 + O) & 7;
        if (i == 0) {                              // j=16,24: kc=2,3
          int kc = j >> 3;
          int aidx = xc + (16 + kc * 4 + lq) * 16 + l15;
          ah = __builtin_bit_cast(v4i, X4h[aidx]);
          al = __builtin_bit_cast(v4i, X4l[aidx]);
        }
        v4i bb = breg[s];
        acch[i] = __builtin_amdgcn_mfma_i32_16x16x64_i8(ah, bb, acch[i], 0, 0, 0);
        accl[i] = __builtin_amdgcn_mfma_i32_16x16x64_i8(al, bb, accl[i], 0, 0, 0);
        const int jn = j + 8;                      // 20..39
        breg[s] = (jn < 32) ? *(const v4i*)(gp0 + (size_t)jn * 1024)
                            : *(const v4i*)(gp1 + (size_t)(jn - 32) * 1024);
      }
    }

    // ---- teacher-forced input (post-L0: short live range) ----
    float4 xa[4], xb[4];
    if (t > 0) {
      const float* xp = target + (size_t)(b0 + myrow) * (TSTEPS * DDIM)
                               + (size_t)(t - 1) * DDIM;
#pragma unroll
      for (int r = 0; r < 4; ++r) {
        xa[r] = *(const float4*)(xp + (size_t)r * (TSTEPS * DDIM));
        xb[r] = *(const float4*)(xp + (size_t)r * (TSTEPS * DDIM) + 4);
      }
    } else {
#pragma unroll
      for (int r = 0; r < 4; ++r) {
        xa[r] = make_float4(0.f, 0.f, 0.f, 0.f);
        xb[r] = make_float4(0.f, 0.f, 0.f, 0.f);
      }
    }

    // ---- deferred out-projection for step t-1 (pre-B reads, post-B writes) ----
    if (t > 0) {
      float s_ = 0.f;
#pragma unroll
      for (int i = 0; i < 16; ++i) {
        ushort4 hx = *(const ushort4*)&h1f[opr * WSTR + i * 16 + opq * 4];
        ushort4 wv = *(const ushort4*)&woutT[opd * WSTR + i * 16 + opq * 4];
        s_ += bf2f(hx.x) * bf2f(wv.x) + bf2f(hx.y) * bf2f(wv.y)
            + bf2f(hx.z) * bf2f(wv.z) + bf2f(hx.w) * bf2f(wv.w);
      }
      s_ += __shfl_xor(s_, 1);
      s_ += __shfl_xor(s_, 2);
      if (opq == 0)
        out[(size_t)(b0 + opr) * (TSTEPS * DDIM) + (size_t)(t - 1) * DDIM + opd] =
            s_ + bo_out;
    }

    // ---- cell 0: dequant + bf16 x-path (wxu unpack); h0(t) -> X_next ----
    {
#pragma unroll
      for (int cc = 0; cc < 2; ++cc) {
        float gf4[4][4];
#pragma unroll
        for (int g = 0; g < 4; ++g) {
          int i = g * 2 + cc;
          int col = g * 256 + jc0 + cc * 16;
          uint4 u = wxu[col];
          float w0 = bfl(u.x), w1 = bfh_(u.x);
          float w2 = bfl(u.y), w3 = bfh_(u.y);
          float w4 = bfl(u.z), w5 = bfh_(u.z);
          float w6 = bfl(u.w), w7 = bfh_(u.w);
          float cs = csA0[i] * sc0;
#pragma unroll
          for (int r = 0; r < 4; ++r)
            gf4[g][r] = ((float)acch[i][r] + (float)accl[i][r] * (1.f / 254.f)) * cs + bA0[i]
                + xa[r].x * w0 + xa[r].y * w1 + xa[r].z * w2 + xa[r].w * w3
                + xb[r].x * w4 + xb[r].y * w5 + xb[r].z * w6 + xb[r].w * w7;
        }
#pragma unroll
        for (int r = 0; r < 4; ++r) {
          float iv = sigm(gf4[0][r]);
          float fv = sigm(gf4[1][r]);
          float gv = tanh_(gf4[2][r]);
          float ov = sigm(gf4[3][r]);
          c0r[cc][r] = fv * c0r[cc][r] + iv * gv;
          char hi, lo;
          q8pair(ov * tanh_(c0r[cc][r]), wq0, &hi, &lo);
          int off = (xn + (16 + 2 * w + cc) * 16 + myrow + r) * 16 + l15;
          Xch[off] = hi; Xcl[off] = lo;
        }
      }
    }
    __syncthreads();   // (B) h0(t) visible; L1 prologue tiles 0..7 landed

    // ====== layer 1: [h1(t-1) | h0(t)] @ W1 (64 tiles, slot = (j+4+O)&7) ======
#pragma unroll
    for (int i = 0; i < 8; ++i) { acch[i] = zi; accl[i] = zi; }
    {
      v4i ah, al;
#pragma unroll 8
      for (int j = 0; j < 64; ++j) {
        const int i = j & 7, s = (j + 4 + O) & 7;
        if (i == 0) {
          int kc = j >> 3;                         // 0..3 h1 (cur), 4..7 h0' (next)
          int aidx = (kc < 4) ? (xc + (kc * 4 + lq) * 16 + l15)
                              : (xn + (16 + (kc - 4) * 4 + lq) * 16 + l15);
          ah = __builtin_bit_cast(v4i, X4h[aidx]);
          al = __builtin_bit_cast(v4i, X4l[aidx]);
        }
        acch[i] = __builtin_amdgcn_mfma_i32_16x16x64_i8(ah, breg[s], acch[i], 0, 0, 0);
        accl[i] = __builtin_amdgcn_mfma_i32_16x16x64_i8(al, breg[s], accl[i], 0, 0, 0);
        const int jn = j + 8;
        // wrap: next-step L0 streamed tiles start at 12 (0..11 are resident)
        breg[s] = (jn < 64) ? *(const v4i*)(gp1 + (size_t)jn * 1024)
                            : *(const v4i*)(gp0 + (size_t)(jn - 64 + 12) * 1024);
      }
    }

    // ---- cell 1: writes h1(t) into X_next + bf16 h1f ----
#pragma unroll
    for (int cc = 0; cc < 2; ++cc)
#pragma unroll
      for (int r = 0; r < 4; ++r) {
        float di = ((float)acch[0 + cc][r] + (float)accl[0 + cc][r] * (1.f / 254.f));
        float df = ((float)acch[2 + cc][r] + (float)accl[2 + cc][r] * (1.f / 254.f));
        float dg = ((float)acch[4 + cc][r] + (float)accl[4 + cc][r] * (1.f / 254.f));
        float dv = ((float)acch[6 + cc][r] + (float)accl[6 + cc][r] * (1.f / 254.f));
        float iv = sigm(di * csA1[0 + cc] * sc1 + bA1[0 + cc]);
        float fv = sigm(df * csA1[2 + cc] * sc1 + bA1[2 + cc]);
        float gv = tanh_(dg * csA1[4 + cc] * sc1 + bA1[4 + cc]);
        float ov = sigm(dv * csA1[6 + cc] * sc1 + bA1[6 + cc]);
        c1r[cc][r] = fv * c1r[cc][r] + iv * gv;
        float h = ov * tanh_(c1r[cc][r]);
        char hi, lo;
        q8pair(h, 127.f, &hi, &lo);
        int off = (xn + (2 * w + cc) * 16 + myrow + r) * 16 + l15;
        Xch[off] = hi; Xcl[off] = lo;
        h1f[(myrow + r) * WSTR + jc0 + cc * 16] = f2bf(h);
      }
    __syncthreads();   // (F) h1(t)/h1f visible; next-step L0 tiles landed
  };

#pragma unroll 1
  for (int t2 = 0; t2 < TSTEPS; t2 += 2) {
    step(t2,     IcO0{});
    step(t2 + 1, IcO4{});
  }

  // ---- epilogue: out-projection for the final step ----
  {
    float s_ = 0.f;
#pragma unroll
    for (int i = 0; i < 16; ++i) {
      ushort4 hx = *(const ushort4*)&h1f[opr * WSTR + i * 16 + opq * 4];
      ushort4 wv = *(const ushort4*)&woutT[opd * WSTR + i * 16 + opq * 4];
      s_ += bf2f(hx.x) * bf2f(wv.x) + bf2f(hx.y) * bf2f(wv.y)
          + bf2f(hx.z) * bf2f(wv.z) + bf2f(hx.w) * bf2f(wv.w);
    }
    s_ += __shfl_xor(s_, 1);
    s_ += __shfl_xor(s_, 2);
    if (opq == 0)
      out[(size_t)(b0 + opr) * (TSTEPS * DDIM) + (size_t)(TSTEPS - 1) * DDIM + opd] =
          s_ + bo_out;
  }
}

extern "C" void kernel_launch(void* const* d_in, const int* in_sizes, int n_in,
                              void* d_out, int out_size, void* d_ws, size_t ws_size,
                              hipStream_t stream) {
  const float* z    = (const float*)d_in[0];
  const float* tgt  = (const float*)d_in[1];
  const float* Wfh  = (const float*)d_in[2];
  const float* bfh  = (const float*)d_in[3];
  const float* Wfc  = (const float*)d_in[4];
  const float* bfc  = (const float*)d_in[5];
  const float* Wih0 = (const float*)d_in[6];
  const float* Whh0 = (const float*)d_in[7];
  const float* bih0 = (const float*)d_in[8];
  const float* bhh0 = (const float*)d_in[9];
  const float* Wih1 = (const float*)d_in[10];
  const float* Whh1 = (const float*)d_in[11];
  const float* bih1 = (const float*)d_in[12];
  const float* bhh1 = (const float*)d_in[13];
  const float* Wout = (const float*)d_in[14];
  const float* bout = (const float*)d_in[15];

  // ws layout (bytes), total ~7.09 MB
  char* ws = (char*)d_ws;
  char*  p0   = ws;                                  // 262,144
  char*  p1   = ws + 262144;                         // 524,288
  char*  h0h  = ws + 786432;                         // 524,288
  char*  h0l  = ws + 1310720;                        // 524,288
  char*  h1h  = ws + 1835008;                        // 524,288
  char*  h1l  = ws + 2359296;                        // 524,288
  float* c0s  = (float*)(ws + 2883584);              // 2,097,152
  float* c1s  = (float*)(ws + 4980736);              // 2,097,152
  float* cs0  = (float*)(ws + 7077888);              // 4,096
  float* qs0  = (float*)(ws + 7081984);              // 4,096
  float* cs1  = (float*)(ws + 7086080);              // 4,096
  float* qs1  = (float*)(ws + 7090176);              // 4,096

  hipLaunchKernelGGL(init_state, dim3(BSZ * HDIM / 256), dim3(256), 0, stream,
                     z, Wfh, bfh, Wfc, bfc, h0h, h0l, h1h, h1l, c0s, c1s);
  hipLaunchKernelGGL(col_scales, dim3(8), dim3(256), 0, stream,
                     Whh0, Wih1, Whh1, cs0, qs0, cs1, qs1);
  hipLaunchKernelGGL(pack_i8, dim3(192), dim3(256), 0, stream,
                     Whh0, Wih1, Whh1, qs0, qs1, p0, p1);
  hipLaunchKernelGGL(lstm_run, dim3(NWG), dim3(NTH), 0, stream,
                     tgt, p0, p1, bih0, bhh0, bih1, bhh1, Wih0, Wout, bout,
                     h0h, h0l, h1h, h1l, c0s, c1s, cs0, cs1, (float*)d_out);
}

// Round 11
// 2740.731 us; speedup vs baseline: 1.2606x; 1.0939x over previous
//
#include <hip/hip_runtime.h>
#include <cstddef>
#include <cstdint>

// 2-layer LSTM decoder, B=2048, Z=64, H=256, D=8, T=250. fp32 in/out.
//
// R20 = R19 (12 resident L0 tiles, breg[8] + period-2 slot offset O, wxu
// bf16 x-tables, single h1f) with the mild spill (R19: VGPR=128, WRITE
// +18 MB scratch) removed by staging x through LDS:
//  - x_lds[2][128] (1 KB): step t stages target[:,t] into buf (t+1)&1
//    right after barrier B; barrier F publishes for step t+1's cell0.
//    Prologue zeros buf 0. No extra barriers.
//  - cell0 hoists x from LDS (8x ds_read_b128, 4-way broadcast): x regs
//    live ONLY inside cell0 (R17's proven-clean peak), not across
//    out-proj; global x address regs gone; 16x-redundant loads gone.
// Stream 672 KB/step, depth 8, slot(j) = (j+4+O)&7 both phases, O alt 0/4
// (seams verified R19, absmax identical). LDS ~161.1 KB of 163.84.
// Go/no-go: VGPR<=124, WRITE ~16 MB, FETCH ~14.5 MB. If WRITE >20 MB the
// 12-resident structure doesn't fit the register budget -> revert R17.

#define BSZ    2048
#define ZDIM   64
#define HDIM   256
#define DDIM   8
#define TSTEPS 250
#define ROWS   16
#define NWG    (BSZ / ROWS)   // 128
#define NTH    512            // 8 waves
#define G4     1024
#define WSTR   264            // h1f/woutT row stride (shorts)

typedef __attribute__((ext_vector_type(4))) int v4i;

struct IcO0 { static constexpr int v = 0; };
struct IcO4 { static constexpr int v = 4; };

__device__ __forceinline__ unsigned short f2bf(float x) {   // RNE f32->bf16
  union { float f; unsigned u; } v; v.f = x;
  unsigned r = v.u + 0x7fff + ((v.u >> 16) & 1);
  return (unsigned short)(r >> 16);
}
__device__ __forceinline__ float bf2f(unsigned short b) {
  union { unsigned u; float f; } v; v.u = (unsigned)b << 16; return v.f;
}
__device__ __forceinline__ float bfl(unsigned u) {          // low bf16 of u32
  union { unsigned u; float f; } v; v.u = u << 16; return v.f;
}
__device__ __forceinline__ float bfh_(unsigned u) {         // high bf16 of u32
  union { unsigned u; float f; } v; v.u = u & 0xffff0000u; return v.f;
}
__device__ __forceinline__ float fexp2(float x) { return __builtin_amdgcn_exp2f(x); }
__device__ __forceinline__ float frcp(float x)  { return __builtin_amdgcn_rcpf(x); }
__device__ __forceinline__ float sigm(float x)  { return frcp(1.f + fexp2(-1.44269504f * x)); }
__device__ __forceinline__ float tanh_(float x) { return 2.f * frcp(1.f + fexp2(-2.88539008f * x)) - 1.f; }
__device__ __forceinline__ char q8(float x, float s) {
  float v = fminf(fmaxf(x * s, -127.f), 127.f);
  return (char)(int)__builtin_rintf(v);
}
// h*s split into hi + lo/254 (lo in [-127,127] exactly since 0.5*254=127)
__device__ __forceinline__ void q8pair(float h, float s, char* hi, char* lo) {
  float hs = fminf(fmaxf(h * s, -127.f), 127.f);
  float hq = __builtin_rintf(hs);
  *hi = (char)(int)hq;
  *lo = (char)(int)__builtin_rintf((hs - hq) * 254.f);
}

// ---------------- initial state (mapping verified R1-R8) ----------------
__global__ void init_state(const float* __restrict__ z,
                           const float* __restrict__ Wfh, const float* __restrict__ bfh,
                           const float* __restrict__ Wfc, const float* __restrict__ bfc,
                           char* __restrict__ h0h, char* __restrict__ h0l,
                           char* __restrict__ h1h, char* __restrict__ h1l,
                           float* __restrict__ c0s, float* __restrict__ c1s)
{
  int idx = blockIdx.x * 256 + threadIdx.x;
  int b = idx >> 8;
  int j = idx & 255;
  int col = ((b & 1) << 8) | j;
  const float* z0 = z + (size_t)(b >> 1) * ZDIM;
  const float* z1 = z + (size_t)(1024 + (b >> 1)) * ZDIM;
  float h0 = bfh[col], c0v = bfc[col], h1 = bfh[col], c1v = bfc[col];
  for (int k = 0; k < ZDIM; ++k) {
    float wh = Wfh[k * 512 + col];
    float wc = Wfc[k * 512 + col];
    float a = z0[k], bb = z1[k];
    h0  += a * wh;  c0v += a * wc;
    h1  += bb * wh; c1v += bb * wc;
  }
  char hi, lo;
  q8pair(h0, 31.75f, &hi, &lo); h0h[idx] = hi; h0l[idx] = lo;
  q8pair(h1, 31.75f, &hi, &lo); h1h[idx] = hi; h1l[idx] = lo;
  c0s[idx] = c0v; c1s[idx] = c1v;
}

// ---------------- per-output-column scales (unchanged) ----------------
__global__ void col_scales(const float* __restrict__ Whh0,
                           const float* __restrict__ Wih1, const float* __restrict__ Whh1,
                           float* __restrict__ cs0, float* __restrict__ qs0,
                           float* __restrict__ cs1, float* __restrict__ qs1)
{
  int c = blockIdx.x * 256 + threadIdx.x;   // 0..2047
  if (c < 1024) {
    float m = 0.f;
    for (int k = 0; k < 256; ++k) m = fmaxf(m, fabsf(Whh0[(size_t)k * G4 + c]));
    cs0[c] = m * (1.f / 16129.f);
    qs0[c] = 127.f / m;
  } else {
    c -= 1024;
    float m = 0.f;
    for (int k = 0; k < 256; ++k) m = fmaxf(m, fabsf(Whh1[(size_t)k * G4 + c]));
    for (int k = 0; k < 256; ++k) m = fmaxf(m, fabsf(Wih1[(size_t)k * G4 + c]));
    cs1[c] = m * (1.f / 16129.f);
    qs1[c] = 127.f / m;
  }
}

// ---- i8 weight pack: per-wave-contiguous linear stream (verified R8) ----
__global__ void pack_i8(const float* __restrict__ Whh0,
                        const float* __restrict__ Wih1, const float* __restrict__ Whh1,
                        const float* __restrict__ qs0, const float* __restrict__ qs1,
                        char* __restrict__ p0, char* __restrict__ p1)
{
  int tt   = blockIdx.x * 4 + (threadIdx.x >> 6);   // 0..767
  int lane = threadIdx.x & 63;
  int l15 = lane & 15, lq = lane >> 4;
  union { char c[16]; uint4 u; } v;
  if (tt < 256) {                                   // layer0: w*4+kc, i
    int w = tt >> 5, kc = (tt >> 3) & 3, i = tt & 7;
    int nt = (i >> 1) * 16 + 2 * w + (i & 1);
    int col = nt * 16 + l15;
    float q = qs0[col];
    for (int j = 0; j < 16; ++j) {
      int k = kc * 64 + lq * 16 + j;
      v.c[j] = q8(Whh0[(size_t)k * G4 + col], q);
    }
    *(uint4*)(p0 + (size_t)tt * 1024 + lane * 16) = v.u;
  } else {                                          // layer1: w*8+kc, i
    int t1 = tt - 256;
    int w = t1 >> 6, kc = (t1 >> 3) & 7, i = t1 & 7;
    int nt = (i >> 1) * 16 + 2 * w + (i & 1);
    int col = nt * 16 + l15;
    float q = qs1[col];
    for (int j = 0; j < 16; ++j) {
      int k = kc * 64 + lq * 16 + j;
      float wv = (k < 256) ? Whh1[(size_t)k * G4 + col]
                           : Wih1[(size_t)(k - 256) * G4 + col];
      v.c[j] = q8(wv, q);
    }
    *(uint4*)(p1 + (size_t)t1 * 1024 + lane * 16) = v.u;
  }
}

// ---------------- persistent LSTM kernel ----------------
__global__ __launch_bounds__(NTH, 1) void lstm_run(
    const float* __restrict__ target,
    const char* __restrict__ p0, const char* __restrict__ p1,
    const float* __restrict__ bih0, const float* __restrict__ bhh0,
    const float* __restrict__ bih1, const float* __restrict__ bhh1,
    const float* __restrict__ Wih0,            // [8,1024] fp32 -> bf16 LDS table
    const float* __restrict__ Wout, const float* __restrict__ bout,
    const char* __restrict__ h0h, const char* __restrict__ h0l,
    const char* __restrict__ h1h, const char* __restrict__ h1l,
    const float* __restrict__ c0s, const float* __restrict__ c1s,
    const float* __restrict__ cs0, const float* __restrict__ cs1,
    float* __restrict__ out)
{
  // double-buffered activation planes: [buf][32 blk-rows * 16], buf = 512 uint4
  __shared__ uint4 X4h[1024];                      // 16 KB
  __shared__ uint4 X4l[1024];                      // 16 KB
  __shared__ unsigned short h1f[16 * WSTR];        // 8.25 KB bf16 h1 (single buf)
  __shared__ unsigned short woutT[8 * WSTR];       // 4.1 KB bf16
  __shared__ uint4 wxu[1024];                      // 16 KB Wih0 bf16x8 per col
  __shared__ uint4 wres[8 * 12 * 64];              // 96 KB resident L0 tiles 0..11
  __shared__ float x_lds[2][128];                  // 1 KB teacher-forced input
                                                   // total ~161.1 KB
  const int tid  = threadIdx.x;
  const int w    = tid >> 6;
  const int lane = tid & 63;
  const int l15  = lane & 15;
  const int lq   = lane >> 4;
  const int b0   = blockIdx.x * ROWS;
  char* Xch = (char*)X4h;
  char* Xcl = (char*)X4l;

  // ---- one-time staging into buffer 0 ----
  {
    int m = tid & 15, blk = tid >> 4;              // 32 blks x 16 m
    const char* sh = (blk < 16) ? h1h : h0h;
    const char* sl = (blk < 16) ? h1l : h0l;
    int jblk = blk & 15;
    X4h[blk * 16 + m] = *(const uint4*)(sh + (size_t)(b0 + m) * HDIM + jblk * 16);
    X4l[blk * 16 + m] = *(const uint4*)(sl + (size_t)(b0 + m) * HDIM + jblk * 16);
  }
  for (int i = tid; i < HDIM * DDIM; i += NTH) {
    int k = i >> 3, d = i & 7;
    woutT[d * WSTR + k] = f2bf(Wout[i]);
  }
  for (int i = tid; i < G4; i += NTH) {            // packed bf16 pairs d={0..7}
    uint4 u;
    u.x = ((unsigned)f2bf(Wih0[1 * G4 + i]) << 16) | f2bf(Wih0[0 * G4 + i]);
    u.y = ((unsigned)f2bf(Wih0[3 * G4 + i]) << 16) | f2bf(Wih0[2 * G4 + i]);
    u.z = ((unsigned)f2bf(Wih0[5 * G4 + i]) << 16) | f2bf(Wih0[4 * G4 + i]);
    u.w = ((unsigned)f2bf(Wih0[7 * G4 + i]) << 16) | f2bf(Wih0[6 * G4 + i]);
    wxu[i] = u;
  }
  if (tid < 128) x_lds[0][tid] = 0.f;              // x(0) = zeros

  const int myrow = lq * 4;
  const int jc0   = 32 * w + l15;
  float c0r[2][4], c1r[2][4];
  float bA0[8], bA1[8], csA0[8], csA1[8];          // flat [g*2+cc]
#pragma unroll
  for (int i = 0; i < 8; ++i) {
    int col = (i >> 1) * 256 + jc0 + 16 * (i & 1);
    bA0[i]  = bih0[col] + bhh0[col];
    bA1[i]  = bih1[col] + bhh1[col];
    csA0[i] = cs0[col];
    csA1[i] = cs1[col];
  }
#pragma unroll
  for (int cc = 0; cc < 2; ++cc) {
    int j = jc0 + cc * 16;
#pragma unroll
    for (int r = 0; r < 4; ++r) {
      c0r[cc][r] = c0s[(size_t)(b0 + myrow + r) * HDIM + j];
      c1r[cc][r] = c1s[(size_t)(b0 + myrow + r) * HDIM + j];
    }
  }
  const int opr = tid >> 5, opd = (tid >> 2) & 7, opq = tid & 3;
  const float bo_out = bout[opd];

  // per-lane weight stream bases; tile j at base + j*1024 (linear)
  const char* gp0 = p0 + (size_t)w * 32768 + lane * 16;
  const char* gp1 = p1 + (size_t)w * 65536 + lane * 16;

  // ---- resident L0 tiles 0..11 (per wave), loaded once ----
#pragma unroll
  for (int j = 0; j < 12; ++j)
    wres[w * 768 + j * 64 + lane] = *(const uint4*)(gp0 + (size_t)j * 1024);

  // 8-deep stream; prologue (O=0): L0 tile 12+s -> slot (12+s+4)&7 = s
  v4i breg[8];
#pragma unroll
  for (int s = 0; s < 8; ++s)
    breg[s] = *(const v4i*)(gp0 + (size_t)(12 + s) * 1024);

  __syncthreads();

  // ---- one LSTM step; O = stream slot offset (0 or 4), compile-time ----
  auto step = [&](int t, auto tag) __attribute__((always_inline)) {
    constexpr int O = decltype(tag)::v;
    const int xc = (t & 1) << 9;                   // uint4-index base of X_cur
    const int xn = xc ^ 512;                       // X_next

    const float sc0 = (t <= 1) ? 4.f : 1.f;
    const float sc1 = (t == 0) ? 4.f : 1.f;
    const float wq0 = (t == 0) ? 31.75f : 127.f;

    v4i acch[8], accl[8];
    const v4i zi = {0, 0, 0, 0};

    // ============ layer 0: h0 @ Whh0 ============
#pragma unroll
    for (int i = 0; i < 8; ++i) { acch[i] = zi; accl[i] = zi; }
    {
      v4i ah, al;
      {                                            // kc=0 A-fragment
        int aidx = xc + (16 + lq) * 16 + l15;
        ah = __builtin_bit_cast(v4i, X4h[aidx]);
        al = __builtin_bit_cast(v4i, X4l[aidx]);
      }
      // resident tiles 0..11 from LDS: 2-slot rotation (static idx)
      {
        v4i rb[2];
        rb[0] = __builtin_bit_cast(v4i, wres[w * 768 + lane]);
#pragma unroll
        for (int j = 0; j < 12; ++j) {
          if (j == 8) {                            // kc=1 A-fragment
            int aidx = xc + (16 + 4 + lq) * 16 + l15;
            ah = __builtin_bit_cast(v4i, X4h[aidx]);
            al = __builtin_bit_cast(v4i, X4l[aidx]);
          }
          if (j < 11)
            rb[(j + 1) & 1] = __builtin_bit_cast(v4i, wres[w * 768 + (j + 1) * 64 + lane]);
          v4i bb = rb[j & 1];
          const int i = j & 7;
          acch[i] = __builtin_amdgcn_mfma_i32_16x16x64_i8(ah, bb, acch[i], 0, 0, 0);
          accl[i] = __builtin_amdgcn_mfma_i32_16x16x64_i8(al, bb, accl[i], 0, 0, 0);
        }
      }
      // streamed tiles 12..31 (slot = (j+4+O)&7); kc=1 frag current at j=12
#pragma unroll
      for (int j = 12; j < 32; ++j) {
        const int i = j & 7, s = (j + 4 + O) & 7;
        if (i == 0) {                              // j=16,24: kc=2,3
          int kc = j >> 3;
          int aidx = xc + (16 + kc * 4 + lq) * 16 + l15;
          ah = __builtin_bit_cast(v4i, X4h[aidx]);
          al = __builtin_bit_cast(v4i, X4l[aidx]);
        }
        v4i bb = breg[s];
        acch[i] = __builtin_amdgcn_mfma_i32_16x16x64_i8(ah, bb, acch[i], 0, 0, 0);
        accl[i] = __builtin_amdgcn_mfma_i32_16x16x64_i8(al, bb, accl[i], 0, 0, 0);
        const int jn = j + 8;                      // 20..39
        breg[s] = (jn < 32) ? *(const v4i*)(gp0 + (size_t)jn * 1024)
                            : *(const v4i*)(gp1 + (size_t)(jn - 32) * 1024);
      }
    }

    // ---- deferred out-projection for step t-1 (pre-B reads, post-B writes) ----
    if (t > 0) {
      float s_ = 0.f;
#pragma unroll
      for (int i = 0; i < 16; ++i) {
        ushort4 hx = *(const ushort4*)&h1f[opr * WSTR + i * 16 + opq * 4];
        ushort4 wv = *(const ushort4*)&woutT[opd * WSTR + i * 16 + opq * 4];
        s_ += bf2f(hx.x) * bf2f(wv.x) + bf2f(hx.y) * bf2f(wv.y)
            + bf2f(hx.z) * bf2f(wv.z) + bf2f(hx.w) * bf2f(wv.w);
      }
      s_ += __shfl_xor(s_, 1);
      s_ += __shfl_xor(s_, 2);
      if (opq == 0)
        out[(size_t)(b0 + opr) * (TSTEPS * DDIM) + (size_t)(t - 1) * DDIM + opd] =
            s_ + bo_out;
    }

    // ---- cell 0: dequant + bf16 x-path (x from LDS); h0(t) -> X_next ----
    {
      float4 xa[4], xb[4];
#pragma unroll
      for (int r = 0; r < 4; ++r) {
        xa[r] = *(const float4*)&x_lds[t & 1][(myrow + r) * 8];
        xb[r] = *(const float4*)&x_lds[t & 1][(myrow + r) * 8 + 4];
      }
#pragma unroll
      for (int cc = 0; cc < 2; ++cc) {
        float gf4[4][4];
#pragma unroll
        for (int g = 0; g < 4; ++g) {
          int i = g * 2 + cc;
          int col = g * 256 + jc0 + cc * 16;
          uint4 u = wxu[col];
          float w0 = bfl(u.x), w1 = bfh_(u.x);
          float w2 = bfl(u.y), w3 = bfh_(u.y);
          float w4 = bfl(u.z), w5 = bfh_(u.z);
          float w6 = bfl(u.w), w7 = bfh_(u.w);
          float cs = csA0[i] * sc0;
#pragma unroll
          for (int r = 0; r < 4; ++r)
            gf4[g][r] = ((float)acch[i][r] + (float)accl[i][r] * (1.f / 254.f)) * cs + bA0[i]
                + xa[r].x * w0 + xa[r].y * w1 + xa[r].z * w2 + xa[r].w * w3
                + xb[r].x * w4 + xb[r].y * w5 + xb[r].z * w6 + xb[r].w * w7;
        }
#pragma unroll
        for (int r = 0; r < 4; ++r) {
          float iv = sigm(gf4[0][r]);
          float fv = sigm(gf4[1][r]);
          float gv = tanh_(gf4[2][r]);
          float ov = sigm(gf4[3][r]);
          c0r[cc][r] = fv * c0r[cc][r] + iv * gv;
          char hi, lo;
          q8pair(ov * tanh_(c0r[cc][r]), wq0, &hi, &lo);
          int off = (xn + (16 + 2 * w + cc) * 16 + myrow + r) * 16 + l15;
          Xch[off] = hi; Xcl[off] = lo;
        }
      }
    }
    __syncthreads();   // (B) h0(t) visible; L1 prologue tiles 0..7 landed

    // ---- stage x(t+1) = target[:, t] into buf (t+1)&1 (published by F) ----
    if (tid < 128) {
      int m = tid >> 3, d = tid & 7;
      x_lds[(t + 1) & 1][tid] =
          target[(size_t)(b0 + m) * (TSTEPS * DDIM) + (size_t)t * DDIM + d];
    }

    // ====== layer 1: [h1(t-1) | h0(t)] @ W1 (64 tiles, slot = (j+4+O)&7) ======
#pragma unroll
    for (int i = 0; i < 8; ++i) { acch[i] = zi; accl[i] = zi; }
    {
      v4i ah, al;
#pragma unroll 8
      for (int j = 0; j < 64; ++j) {
        const int i = j & 7, s = (j + 4 + O) & 7;
        if (i == 0) {
          int kc = j >> 3;                         // 0..3 h1 (cur), 4..7 h0' (next)
          int aidx = (kc < 4) ? (xc + (kc * 4 + lq) * 16 + l15)
                              : (xn + (16 + (kc - 4) * 4 + lq) * 16 + l15);
          ah = __builtin_bit_cast(v4i, X4h[aidx]);
          al = __builtin_bit_cast(v4i, X4l[aidx]);
        }
        acch[i] = __builtin_amdgcn_mfma_i32_16x16x64_i8(ah, breg[s], acch[i], 0, 0, 0);
        accl[i] = __builtin_amdgcn_mfma_i32_16x16x64_i8(al, breg[s], accl[i], 0, 0, 0);
        const int jn = j + 8;
        // wrap: next-step L0 streamed tiles start at 12 (0..11 are resident)
        breg[s] = (jn < 64) ? *(const v4i*)(gp1 + (size_t)jn * 1024)
                            : *(const v4i*)(gp0 + (size_t)(jn - 64 + 12) * 1024);
      }
    }

    // ---- cell 1: writes h1(t) into X_next + bf16 h1f ----
#pragma unroll
    for (int cc = 0; cc < 2; ++cc)
#pragma unroll
      for (int r = 0; r < 4; ++r) {
        float di = ((float)acch[0 + cc][r] + (float)accl[0 + cc][r] * (1.f / 254.f));
        float df = ((float)acch[2 + cc][r] + (float)accl[2 + cc][r] * (1.f / 254.f));
        float dg = ((float)acch[4 + cc][r] + (float)accl[4 + cc][r] * (1.f / 254.f));
        float dv = ((float)acch[6 + cc][r] + (float)accl[6 + cc][r] * (1.f / 254.f));
        float iv = sigm(di * csA1[0 + cc] * sc1 + bA1[0 + cc]);
        float fv = sigm(df * csA1[2 + cc] * sc1 + bA1[2 + cc]);
        float gv = tanh_(dg * csA1[4 + cc] * sc1 + bA1[4 + cc]);
        float ov = sigm(dv * csA1[6 + cc] * sc1 + bA1[6 + cc]);
        c1r[cc][r] = fv * c1r[cc][r] + iv * gv;
        float h = ov * tanh_(c1r[cc][r]);
        char hi, lo;
        q8pair(h, 127.f, &hi, &lo);
        int off = (xn + (2 * w + cc) * 16 + myrow + r) * 16 + l15;
        Xch[off] = hi; Xcl[off] = lo;
        h1f[(myrow + r) * WSTR + jc0 + cc * 16] = f2bf(h);
      }
    __syncthreads();   // (F) h1(t)/h1f/x(t+1) visible; next L0 tiles landed
  };

#pragma unroll 1
  for (int t2 = 0; t2 < TSTEPS; t2 += 2) {
    step(t2,     IcO0{});
    step(t2 + 1, IcO4{});
  }

  // ---- epilogue: out-projection for the final step ----
  {
    float s_ = 0.f;
#pragma unroll
    for (int i = 0; i < 16; ++i) {
      ushort4 hx = *(const ushort4*)&h1f[opr * WSTR + i * 16 + opq * 4];
      ushort4 wv = *(const ushort4*)&woutT[opd * WSTR + i * 16 + opq * 4];
      s_ += bf2f(hx.x) * bf2f(wv.x) + bf2f(hx.y) * bf2f(wv.y)
          + bf2f(hx.z) * bf2f(wv.z) + bf2f(hx.w) * bf2f(wv.w);
    }
    s_ += __shfl_xor(s_, 1);
    s_ += __shfl_xor(s_, 2);
    if (opq == 0)
      out[(size_t)(b0 + opr) * (TSTEPS * DDIM) + (size_t)(TSTEPS - 1) * DDIM + opd] =
          s_ + bo_out;
  }
}

extern "C" void kernel_launch(void* const* d_in, const int* in_sizes, int n_in,
                              void* d_out, int out_size, void* d_ws, size_t ws_size,
                              hipStream_t stream) {
  const float* z    = (const float*)d_in[0];
  const float* tgt  = (const float*)d_in[1];
  const float* Wfh  = (const float*)d_in[2];
  const float* bfh  = (const float*)d_in[3];
  const float* Wfc  = (const float*)d_in[4];
  const float* bfc  = (const float*)d_in[5];
  const float* Wih0 = (const float*)d_in[6];
  const float* Whh0 = (const float*)d_in[7];
  const float* bih0 = (const float*)d_in[8];
  const float* bhh0 = (const float*)d_in[9];
  const float* Wih1 = (const float*)d_in[10];
  const float* Whh1 = (const float*)d_in[11];
  const float* bih1 = (const float*)d_in[12];
  const float* bhh1 = (const float*)d_in[13];
  const float* Wout = (const float*)d_in[14];
  const float* bout = (const float*)d_in[15];

  // ws layout (bytes), total ~7.09 MB
  char* ws = (char*)d_ws;
  char*  p0   = ws;                                  // 262,144
  char*  p1   = ws + 262144;                         // 524,288
  char*  h0h  = ws + 786432;                         // 524,288
  char*  h0l  = ws + 1310720;                        // 524,288
  char*  h1h  = ws + 1835008;                        // 524,288
  char*  h1l  = ws + 2359296;                        // 524,288
  float* c0s  = (float*)(ws + 2883584);              // 2,097,152
  float* c1s  = (float*)(ws + 4980736);              // 2,097,152
  float* cs0  = (float*)(ws + 7077888);              // 4,096
  float* qs0  = (float*)(ws + 7081984);              // 4,096
  float* cs1  = (float*)(ws + 7086080);              // 4,096
  float* qs1  = (float*)(ws + 7090176);              // 4,096

  hipLaunchKernelGGL(init_state, dim3(BSZ * HDIM / 256), dim3(256), 0, stream,
                     z, Wfh, bfh, Wfc, bfc, h0h, h0l, h1h, h1l, c0s, c1s);
  hipLaunchKernelGGL(col_scales, dim3(8), dim3(256), 0, stream,
                     Whh0, Wih1, Whh1, cs0, qs0, cs1, qs1);
  hipLaunchKernelGGL(pack_i8, dim3(192), dim3(256), 0, stream,
                     Whh0, Wih1, Whh1, qs0, qs1, p0, p1);
  hipLaunchKernelGGL(lstm_run, dim3(NWG), dim3(NTH), 0, stream,
                     tgt, p0, p1, bih0, bhh0, bih1, bhh1, Wih0, Wout, bout,
                     h0h, h0l, h1h, h1l, c0s, c1s, cs0, cs1, (float*)d_out);
}